// Round 5
// baseline (816.255 us; speedup 1.0000x reference)
//
#include <hip/hip_runtime.h>
#include <hip/hip_bf16.h>

#define EPS 1e-5f

// ---------------------------------------------------------------- histogram + rank
// rank[e] = arrival order of edge e within its dst. One atomic pass; rank is
// written LINEARLY (streaming, non-temporal: keep L2 for the counts RMWs).
__global__ __launch_bounds__(256) void k_histrank(const int* __restrict__ dst,
                                                  int* __restrict__ counts,
                                                  int* __restrict__ rank, int nE) {
    int i = blockIdx.x * 256 + threadIdx.x;
    if (i < nE) {
        int p = atomicAdd(&counts[dst[i]], 1);
        __builtin_nontemporal_store(p, &rank[i]);
    }
}

// ---------------------------------------------------------------- scan (3 phases)
__global__ __launch_bounds__(256) void k_scan1(const int* __restrict__ counts,
                                               int* __restrict__ bsums, int n) {
    __shared__ int sdata[256];
    int base = blockIdx.x * 2048;
    int t = threadIdx.x;
    int s = 0;
#pragma unroll
    for (int i = 0; i < 8; ++i) {
        int idx = base + t * 8 + i;
        if (idx < n) s += counts[idx];
    }
    sdata[t] = s;
    __syncthreads();
    for (int off = 128; off > 0; off >>= 1) {
        if (t < off) sdata[t] += sdata[t + off];
        __syncthreads();
    }
    if (t == 0) bsums[blockIdx.x] = sdata[0];
}

__global__ __launch_bounds__(64) void k_scan2(int* __restrict__ bsums, int nb) {
    if (threadIdx.x == 0 && blockIdx.x == 0) {
        int acc = 0;
        for (int i = 0; i < nb; ++i) { int v = bsums[i]; bsums[i] = acc; acc += v; }
    }
}

__global__ __launch_bounds__(256) void k_scan3(const int* __restrict__ counts,
                                               const int* __restrict__ bsums,
                                               int* __restrict__ rowstart,
                                               int n, int nE) {
    __shared__ int sth[256];
    int base = blockIdx.x * 2048;
    int t = threadIdx.x;
    int loc[8];
    int s = 0;
#pragma unroll
    for (int i = 0; i < 8; ++i) {
        int idx = base + t * 8 + i;
        loc[i] = s;
        s += (idx < n) ? counts[idx] : 0;
    }
    sth[t] = s;
    __syncthreads();
    for (int off = 1; off < 256; off <<= 1) {
        int tmp = (t >= off) ? sth[t - off] : 0;
        __syncthreads();
        sth[t] += tmp;
        __syncthreads();
    }
    int excl = sth[t] - s + bsums[blockIdx.x];
#pragma unroll
    for (int i = 0; i < 8; ++i) {
        int idx = base + t * 8 + i;
        if (idx < n) rowstart[idx] = excl + loc[i];
    }
    if (blockIdx.x == 0 && t == 0) rowstart[n] = nE;
}

// ---------------------------------------------------------------- CSR fill (no atomics)
__global__ __launch_bounds__(256) void k_fill3(const int* __restrict__ srci,
                                               const int* __restrict__ dsti,
                                               const int* __restrict__ rank,
                                               const int* __restrict__ rowstart,
                                               int* __restrict__ col, int nE) {
    int e = blockIdx.x * 256 + threadIdx.x;
    if (e < nE) {
        col[rowstart[dsti[e]] + rank[e]] = srci[e];
    }
}

// ---------------------------------------------------------------- linear (layer 1)
__global__ __launch_bounds__(256) void k_linear(const float* __restrict__ X,
                                                const float* __restrict__ W,
                                                const float* __restrict__ bias,
                                                float* __restrict__ out,
                                                int nRows) {
    __shared__ float xs[64][132];
    int row0 = blockIdx.x * 64;
    int tid = threadIdx.x;
    for (int i = tid; i < 64 * 32; i += 256) {
        int r = i >> 5, c4 = (i & 31) << 2;
        float4 v = make_float4(0.f, 0.f, 0.f, 0.f);
        int row = row0 + r;
        if (row < nRows) v = *(const float4*)(X + (size_t)row * 128 + c4);
        *(float4*)&xs[r][c4] = v;
    }
    __syncthreads();

    int cg = tid & 15, rg = tid >> 4;
    int c0 = cg * 8, r0 = rg * 4;
    float acc[4][8];
    float4 b0 = *(const float4*)(bias + c0);
    float4 b1 = *(const float4*)(bias + c0 + 4);
#pragma unroll
    for (int r = 0; r < 4; ++r) {
        acc[r][0] = b0.x; acc[r][1] = b0.y; acc[r][2] = b0.z; acc[r][3] = b0.w;
        acc[r][4] = b1.x; acc[r][5] = b1.y; acc[r][6] = b1.z; acc[r][7] = b1.w;
    }

    for (int k0 = 0; k0 < 128; k0 += 4) {
        float4 xv[4];
#pragma unroll
        for (int r = 0; r < 4; ++r) xv[r] = *(const float4*)&xs[r0 + r][k0];
#pragma unroll
        for (int kk = 0; kk < 4; ++kk) {
            int k = k0 + kk;
            float4 w0 = *(const float4*)(W + k * 128 + c0);
            float4 w1 = *(const float4*)(W + k * 128 + c0 + 4);
            float wv[8] = {w0.x, w0.y, w0.z, w0.w, w1.x, w1.y, w1.z, w1.w};
#pragma unroll
            for (int r = 0; r < 4; ++r) {
                float xk = (&xv[r].x)[kk];
#pragma unroll
                for (int j = 0; j < 8; ++j) acc[r][j] = fmaf(xk, wv[j], acc[r][j]);
            }
        }
    }

#pragma unroll
    for (int r = 0; r < 4; ++r) {
        int row = row0 + r0 + r;
        if (row >= nRows) continue;
        *(float4*)(out + (size_t)row * 128 + c0) =
            make_float4(acc[r][0], acc[r][1], acc[r][2], acc[r][3]);
        *(float4*)(out + (size_t)row * 128 + c0 + 4) =
            make_float4(acc[r][4], acc[r][5], acc[r][6], acc[r][7]);
    }
}

// ---------------------------------------------------------------- gather+bn+relu+linear
// 512 threads = 8 waves; 32 rows/block (4 rows per wave).
// phase A: mean-gather + BN + ReLU -> LDS tile [32][128]
// phase B: tile @ W[128][128] + bias -> out rows (W read from global, L2-hot)
__global__ __launch_bounds__(512) void k_glin(const float* __restrict__ src,
                                              const int* __restrict__ rowstart,
                                              const int* __restrict__ col,
                                              const float* __restrict__ g,
                                              const float* __restrict__ be,
                                              const float* __restrict__ m,
                                              const float* __restrict__ v,
                                              const float* __restrict__ W,
                                              const float* __restrict__ bias,
                                              float* __restrict__ out, int nRows) {
    __shared__ float xs[32][132];
    int row0 = blockIdx.x * 32;
    int tid = threadIdx.x;
    int wid = tid >> 6, lane = tid & 63;
    int d0 = lane * 2;

    float2 gv  = *(const float2*)(g + d0);
    float2 bev = *(const float2*)(be + d0);
    float2 mv  = *(const float2*)(m + d0);
    float2 vv  = *(const float2*)(v + d0);
    float sx = rsqrtf(vv.x + EPS) * gv.x;
    float sy = rsqrtf(vv.y + EPS) * gv.y;

#pragma unroll
    for (int rr = 0; rr < 4; ++rr) {
        int lr = wid * 4 + rr;
        int r = row0 + lr;
        float2 o = make_float2(0.f, 0.f);
        if (r < nRows) {
            int s = rowstart[r], e = rowstart[r + 1];
            float2 acc = *(const float2*)(src + (size_t)r * 128 + d0);   // self loop
            int j = s;
            for (; j + 8 <= e; j += 8) {
                int ci[8];
#pragma unroll
                for (int u = 0; u < 8; ++u) ci[u] = col[j + u];
                float2 t[8];
#pragma unroll
                for (int u = 0; u < 8; ++u)
                    t[u] = *(const float2*)(src + (size_t)ci[u] * 128 + d0);
#pragma unroll
                for (int u = 0; u < 8; ++u) { acc.x += t[u].x; acc.y += t[u].y; }
            }
            for (; j < e; ++j) {
                int ci = col[j];
                float2 a = *(const float2*)(src + (size_t)ci * 128 + d0);
                acc.x += a.x; acc.y += a.y;
            }
            float rc = 1.0f / (float)(e - s + 1);
            o.x = fmaxf((acc.x * rc - mv.x) * sx + bev.x, 0.f);
            o.y = fmaxf((acc.y * rc - mv.y) * sy + bev.y, 0.f);
        }
        *(float2*)&xs[lr][d0] = o;
    }
    __syncthreads();

    // 32x128 tile @ W + bias; thread = 1 row x 8 cols
    int cg = tid & 15, rg = tid >> 4;          // cg 0..15, rg 0..31
    int c0 = cg * 8;
    float acc[8];
    float4 b0 = *(const float4*)(bias + c0);
    float4 b1 = *(const float4*)(bias + c0 + 4);
    acc[0] = b0.x; acc[1] = b0.y; acc[2] = b0.z; acc[3] = b0.w;
    acc[4] = b1.x; acc[5] = b1.y; acc[6] = b1.z; acc[7] = b1.w;

    for (int k0 = 0; k0 < 128; k0 += 4) {
        float4 xv = *(const float4*)&xs[rg][k0];
#pragma unroll
        for (int kk = 0; kk < 4; ++kk) {
            int k = k0 + kk;
            float4 w0 = *(const float4*)(W + k * 128 + c0);
            float4 w1 = *(const float4*)(W + k * 128 + c0 + 4);
            float xk = (&xv.x)[kk];
            acc[0] = fmaf(xk, w0.x, acc[0]);
            acc[1] = fmaf(xk, w0.y, acc[1]);
            acc[2] = fmaf(xk, w0.z, acc[2]);
            acc[3] = fmaf(xk, w0.w, acc[3]);
            acc[4] = fmaf(xk, w1.x, acc[4]);
            acc[5] = fmaf(xk, w1.y, acc[5]);
            acc[6] = fmaf(xk, w1.z, acc[6]);
            acc[7] = fmaf(xk, w1.w, acc[7]);
        }
    }

    int orow = row0 + rg;
    if (orow < nRows) {
        *(float4*)(out + (size_t)orow * 128 + c0) =
            make_float4(acc[0], acc[1], acc[2], acc[3]);
        *(float4*)(out + (size_t)orow * 128 + c0 + 4) =
            make_float4(acc[4], acc[5], acc[6], acc[7]);
    }
}

// ---------------------------------------------------------------- gather+bn+relu+MLP head
// phase A: mean-gather + BN2 + ReLU -> LDS [32][128]
// phase B: hid = relu(tile @ Wc1 + bc1) -> LDS [32][64]
// phase C: out = hid @ Wc2 + bc2 -> [32][2]
__global__ __launch_bounds__(512) void k_ghead(const float* __restrict__ src,
                                               const int* __restrict__ rowstart,
                                               const int* __restrict__ col,
                                               const float* __restrict__ g,
                                               const float* __restrict__ be,
                                               const float* __restrict__ m,
                                               const float* __restrict__ v,
                                               const float* __restrict__ Wc1,
                                               const float* __restrict__ bc1,
                                               const float* __restrict__ Wc2,
                                               const float* __restrict__ bc2,
                                               float* __restrict__ out, int nRows) {
    __shared__ float xs[32][132];
    __shared__ float hs[32][68];
    int row0 = blockIdx.x * 32;
    int tid = threadIdx.x;
    int wid = tid >> 6, lane = tid & 63;
    int d0 = lane * 2;

    float2 gv  = *(const float2*)(g + d0);
    float2 bev = *(const float2*)(be + d0);
    float2 mv  = *(const float2*)(m + d0);
    float2 vv  = *(const float2*)(v + d0);
    float sx = rsqrtf(vv.x + EPS) * gv.x;
    float sy = rsqrtf(vv.y + EPS) * gv.y;

#pragma unroll
    for (int rr = 0; rr < 4; ++rr) {
        int lr = wid * 4 + rr;
        int r = row0 + lr;
        float2 o = make_float2(0.f, 0.f);
        if (r < nRows) {
            int s = rowstart[r], e = rowstart[r + 1];
            float2 acc = *(const float2*)(src + (size_t)r * 128 + d0);   // self loop
            int j = s;
            for (; j + 8 <= e; j += 8) {
                int ci[8];
#pragma unroll
                for (int u = 0; u < 8; ++u) ci[u] = col[j + u];
                float2 t[8];
#pragma unroll
                for (int u = 0; u < 8; ++u)
                    t[u] = *(const float2*)(src + (size_t)ci[u] * 128 + d0);
#pragma unroll
                for (int u = 0; u < 8; ++u) { acc.x += t[u].x; acc.y += t[u].y; }
            }
            for (; j < e; ++j) {
                int ci = col[j];
                float2 a = *(const float2*)(src + (size_t)ci * 128 + d0);
                acc.x += a.x; acc.y += a.y;
            }
            float rc = 1.0f / (float)(e - s + 1);
            o.x = fmaxf((acc.x * rc - mv.x) * sx + bev.x, 0.f);
            o.y = fmaxf((acc.y * rc - mv.y) * sy + bev.y, 0.f);
        }
        *(float2*)&xs[lr][d0] = o;
    }
    __syncthreads();

    // hid = relu(xs @ Wc1 + bc1): 32x64, thread = 1 row x 4 cols
    int cg = tid & 15, rg = tid >> 4;
    int c0 = cg * 4;
    float acc[4];
    float4 bc = *(const float4*)(bc1 + c0);
    acc[0] = bc.x; acc[1] = bc.y; acc[2] = bc.z; acc[3] = bc.w;
    for (int k0 = 0; k0 < 128; k0 += 4) {
        float4 xv = *(const float4*)&xs[rg][k0];
#pragma unroll
        for (int kk = 0; kk < 4; ++kk) {
            float4 w4 = *(const float4*)(Wc1 + (k0 + kk) * 64 + c0);
            float xk = (&xv.x)[kk];
            acc[0] = fmaf(xk, w4.x, acc[0]);
            acc[1] = fmaf(xk, w4.y, acc[1]);
            acc[2] = fmaf(xk, w4.z, acc[2]);
            acc[3] = fmaf(xk, w4.w, acc[3]);
        }
    }
    *(float4*)&hs[rg][c0] = make_float4(fmaxf(acc[0], 0.f), fmaxf(acc[1], 0.f),
                                        fmaxf(acc[2], 0.f), fmaxf(acc[3], 0.f));
    __syncthreads();

    // logits: 32 rows x 2
    if (tid < 64) {
        int r = tid >> 1, oc = tid & 1;
        float s = bc2[oc];
        for (int c = 0; c < 64; ++c) s = fmaf(hs[r][c], Wc2[c * 2 + oc], s);
        int row = row0 + r;
        if (row < nRows) out[(size_t)row * 2 + oc] = s;
    }
}

// ---------------------------------------------------------------- launch
extern "C" void kernel_launch(void* const* d_in, const int* in_sizes, int n_in,
                              void* d_out, int out_size, void* d_ws, size_t ws_size,
                              hipStream_t stream) {
    const float* x   = (const float*)d_in[0];
    const int*   ei  = (const int*)d_in[1];
    const float* W1  = (const float*)d_in[2];
    const float* b1  = (const float*)d_in[3];
    const float* g1  = (const float*)d_in[4];
    const float* be1 = (const float*)d_in[5];
    const float* m1  = (const float*)d_in[6];
    const float* v1  = (const float*)d_in[7];
    const float* W2  = (const float*)d_in[8];
    const float* b2  = (const float*)d_in[9];
    const float* g2  = (const float*)d_in[10];
    const float* be2 = (const float*)d_in[11];
    const float* m2  = (const float*)d_in[12];
    const float* v2  = (const float*)d_in[13];
    const float* Wc1 = (const float*)d_in[14];
    const float* bc1 = (const float*)d_in[15];
    const float* Wc2 = (const float*)d_in[16];
    const float* bc2 = (const float*)d_in[17];

    const int N_ = in_sizes[0] / 128;
    const int E_ = in_sizes[1] / 2;
    const int* srci = ei;
    const int* dsti = ei + E_;

    float* A = (float*)d_ws;                       // [N,128]
    float* B = A + (size_t)N_ * 128;               // [N,128]; rank aliases B
    int* rank = (int*)B;                           // [E] int, dead before k_glin
    int* counts   = (int*)(B + (size_t)N_ * 128);  // N
    int* rowstart = counts + N_;                   // N+1
    int* bsums    = rowstart + N_ + 1;             // 256
    int* col      = bsums + 256;                   // E

    const int nb = (N_ + 2047) / 2048;

    // ---- CSR build (rank trick: single atomic pass, atomic-free fill)
    hipMemsetAsync(counts, 0, (size_t)N_ * sizeof(int), stream);
    k_histrank<<<(E_ + 255) / 256, 256, 0, stream>>>(dsti, counts, rank, E_);
    k_scan1   <<<nb, 256, 0, stream>>>(counts, bsums, N_);
    k_scan2   <<<1, 64, 0, stream>>>(bsums, nb);
    k_scan3   <<<nb, 256, 0, stream>>>(counts, bsums, rowstart, N_, E_);
    k_fill3   <<<(E_ + 255) / 256, 256, 0, stream>>>(srci, dsti, rank, rowstart,
                                                     col, E_);

    // ---- layer 1 linear
    k_linear<<<(N_ + 63) / 64, 256, 0, stream>>>(x, W1, b1, A, N_);

    // ---- gather1 + bn1 + relu + layer-2 linear (fused)
    k_glin<<<(N_ + 31) / 32, 512, 0, stream>>>(A, rowstart, col,
                                               g1, be1, m1, v1,
                                               W2, b2, B, N_);

    // ---- gather2 + bn2 + relu + MLP head (fused)
    k_ghead<<<(N_ + 31) / 32, 512, 0, stream>>>(B, rowstart, col,
                                                g2, be2, m2, v2,
                                                Wc1, bc1, Wc2, bc2,
                                                (float*)d_out, N_);
}

// Round 6
// 655.613 us; speedup vs baseline: 1.2450x; 1.2450x over previous
//
#include <hip/hip_runtime.h>
#include <hip/hip_bf16.h>

#define EPS 1e-5f

// ---------------------------------------------------------------- linear tile (device)
// one 64-row x 128-col tile of out = X @ W + bias, 256 threads
__device__ __forceinline__ void lin_tile(const float* __restrict__ X,
                                         const float* __restrict__ W,
                                         const float* __restrict__ bias,
                                         float* __restrict__ out,
                                         float (*xs)[132],
                                         int row0, int rowLim, int tid) {
    for (int i = tid; i < 64 * 32; i += 256) {
        int r = i >> 5, c4 = (i & 31) << 2;
        float4 v = make_float4(0.f, 0.f, 0.f, 0.f);
        int row = row0 + r;
        if (row < rowLim) v = *(const float4*)(X + (size_t)row * 128 + c4);
        *(float4*)&xs[r][c4] = v;
    }
    __syncthreads();

    int cg = tid & 15, rg = tid >> 4;
    int c0 = cg * 8, r0 = rg * 4;
    float acc[4][8];
    float4 b0 = *(const float4*)(bias + c0);
    float4 b1 = *(const float4*)(bias + c0 + 4);
#pragma unroll
    for (int r = 0; r < 4; ++r) {
        acc[r][0] = b0.x; acc[r][1] = b0.y; acc[r][2] = b0.z; acc[r][3] = b0.w;
        acc[r][4] = b1.x; acc[r][5] = b1.y; acc[r][6] = b1.z; acc[r][7] = b1.w;
    }

    for (int k0 = 0; k0 < 128; k0 += 4) {
        float4 xv[4];
#pragma unroll
        for (int r = 0; r < 4; ++r) xv[r] = *(const float4*)&xs[r0 + r][k0];
#pragma unroll
        for (int kk = 0; kk < 4; ++kk) {
            int k = k0 + kk;
            float4 w0 = *(const float4*)(W + k * 128 + c0);
            float4 w1 = *(const float4*)(W + k * 128 + c0 + 4);
            float wv[8] = {w0.x, w0.y, w0.z, w0.w, w1.x, w1.y, w1.z, w1.w};
#pragma unroll
            for (int r = 0; r < 4; ++r) {
                float xk = (&xv[r].x)[kk];
#pragma unroll
                for (int j = 0; j < 8; ++j) acc[r][j] = fmaf(xk, wv[j], acc[r][j]);
            }
        }
    }

#pragma unroll
    for (int r = 0; r < 4; ++r) {
        int row = row0 + r0 + r;
        if (row >= rowLim) continue;
        *(float4*)(out + (size_t)row * 128 + c0) =
            make_float4(acc[r][0], acc[r][1], acc[r][2], acc[r][3]);
        *(float4*)(out + (size_t)row * 128 + c0 + 4) =
            make_float4(acc[r][4], acc[r][5], acc[r][6], acc[r][7]);
    }
}

// ---------------------------------------------------------------- histrank + linear (merged)
// blocks [0,HB): rank[e] = atomicAdd(&counts[dst[e]],1)  (CSR pass 1)
// blocks [HB,..): linear-1 on rows [0, rowLim1)
__global__ __launch_bounds__(256) void k_hist_lin(const int* __restrict__ dst,
                                                  int* __restrict__ counts,
                                                  int* __restrict__ rank, int nE, int HB,
                                                  const float* __restrict__ X,
                                                  const float* __restrict__ W,
                                                  const float* __restrict__ bias,
                                                  float* __restrict__ out, int rowLim1) {
    __shared__ float xs[64][132];
    int bid = blockIdx.x;
    if (bid < HB) {
        int i = bid * 256 + threadIdx.x;
        if (i < nE) {
            int p = atomicAdd(&counts[dst[i]], 1);
            __builtin_nontemporal_store(p, &rank[i]);
        }
    } else {
        lin_tile(X, W, bias, out, xs, (bid - HB) * 64, rowLim1, threadIdx.x);
    }
}

// ---------------------------------------------------------------- fill + linear (merged)
// blocks [0,FB): col[rowstart[dst]+rank] = src  (CSR pass 2, no atomics)
// blocks [FB,..): linear-1 on rows [row0_2, nRows)
__global__ __launch_bounds__(256) void k_fill_lin(const int* __restrict__ srci,
                                                  const int* __restrict__ dsti,
                                                  const int* __restrict__ rank,
                                                  const int* __restrict__ rowstart,
                                                  int* __restrict__ col, int nE, int FB,
                                                  const float* __restrict__ X,
                                                  const float* __restrict__ W,
                                                  const float* __restrict__ bias,
                                                  float* __restrict__ out,
                                                  int row0_2, int nRows) {
    __shared__ float xs[64][132];
    int bid = blockIdx.x;
    if (bid < FB) {
        int e = bid * 256 + threadIdx.x;
        if (e < nE) col[rowstart[dsti[e]] + rank[e]] = srci[e];
    } else {
        lin_tile(X, W, bias, out, xs, row0_2 + (bid - FB) * 64, nRows, threadIdx.x);
    }
}

// ---------------------------------------------------------------- scan (3 phases)
__global__ __launch_bounds__(256) void k_scan1(const int* __restrict__ counts,
                                               int* __restrict__ bsums, int n) {
    __shared__ int sdata[256];
    int base = blockIdx.x * 2048;
    int t = threadIdx.x;
    int s = 0;
#pragma unroll
    for (int i = 0; i < 8; ++i) {
        int idx = base + t * 8 + i;
        if (idx < n) s += counts[idx];
    }
    sdata[t] = s;
    __syncthreads();
    for (int off = 128; off > 0; off >>= 1) {
        if (t < off) sdata[t] += sdata[t + off];
        __syncthreads();
    }
    if (t == 0) bsums[blockIdx.x] = sdata[0];
}

__global__ __launch_bounds__(64) void k_scan2(int* __restrict__ bsums, int nb) {
    if (threadIdx.x == 0 && blockIdx.x == 0) {
        int acc = 0;
        for (int i = 0; i < nb; ++i) { int v = bsums[i]; bsums[i] = acc; acc += v; }
    }
}

__global__ __launch_bounds__(256) void k_scan3(const int* __restrict__ counts,
                                               const int* __restrict__ bsums,
                                               int* __restrict__ rowstart,
                                               int n, int nE) {
    __shared__ int sth[256];
    int base = blockIdx.x * 2048;
    int t = threadIdx.x;
    int loc[8];
    int s = 0;
#pragma unroll
    for (int i = 0; i < 8; ++i) {
        int idx = base + t * 8 + i;
        loc[i] = s;
        s += (idx < n) ? counts[idx] : 0;
    }
    sth[t] = s;
    __syncthreads();
    for (int off = 1; off < 256; off <<= 1) {
        int tmp = (t >= off) ? sth[t - off] : 0;
        __syncthreads();
        sth[t] += tmp;
        __syncthreads();
    }
    int excl = sth[t] - s + bsums[blockIdx.x];
#pragma unroll
    for (int i = 0; i < 8; ++i) {
        int idx = base + t * 8 + i;
        if (idx < n) rowstart[idx] = excl + loc[i];
    }
    if (blockIdx.x == 0 && t == 0) rowstart[n] = nE;
}

// ---------------------------------------------------------------- linear (standalone, layer 2)
__global__ __launch_bounds__(256) void k_linear(const float* __restrict__ X,
                                                const float* __restrict__ W,
                                                const float* __restrict__ bias,
                                                float* __restrict__ out,
                                                int nRows) {
    __shared__ float xs[64][132];
    lin_tile(X, W, bias, out, xs, blockIdx.x * 64, nRows, threadIdx.x);
}

// ---------------------------------------------------------------- gather (round-4 verbatim)
template <bool FUSE_BN>
__global__ __launch_bounds__(256) void k_gather(const float* __restrict__ src,
                                                const int* __restrict__ rowstart,
                                                const int* __restrict__ col,
                                                const float* __restrict__ g,
                                                const float* __restrict__ be,
                                                const float* __restrict__ m,
                                                const float* __restrict__ v,
                                                float* __restrict__ out, int nRows) {
    int r = blockIdx.x * 4 + (threadIdx.x >> 6);
    if (r >= nRows) return;
    int lane = threadIdx.x & 63;
    int d0 = lane * 2;
    int s = rowstart[r], e = rowstart[r + 1];

    float2 acc = *(const float2*)(src + (size_t)r * 128 + d0);   // self loop
    int j = s;
    for (; j + 8 <= e; j += 8) {
        int ci[8];
#pragma unroll
        for (int u = 0; u < 8; ++u) ci[u] = col[j + u];
        float2 t[8];
#pragma unroll
        for (int u = 0; u < 8; ++u)
            t[u] = *(const float2*)(src + (size_t)ci[u] * 128 + d0);
#pragma unroll
        for (int u = 0; u < 8; ++u) { acc.x += t[u].x; acc.y += t[u].y; }
    }
    for (; j < e; ++j) {
        int ci = col[j];
        float2 a = *(const float2*)(src + (size_t)ci * 128 + d0);
        acc.x += a.x;
        acc.y += a.y;
    }
    float rc = 1.0f / (float)(e - s + 1);
    float2 o;
    if (FUSE_BN) {
        float2 gv = *(const float2*)(g + d0);
        float2 bev = *(const float2*)(be + d0);
        float2 mv = *(const float2*)(m + d0);
        float2 vv = *(const float2*)(v + d0);
        o.x = fmaxf((acc.x * rc - mv.x) * rsqrtf(vv.x + EPS) * gv.x + bev.x, 0.f);
        o.y = fmaxf((acc.y * rc - mv.y) * rsqrtf(vv.y + EPS) * gv.y + bev.y, 0.f);
    } else {
        o.x = acc.x * rc;
        o.y = acc.y * rc;
    }
    *(float2*)(out + (size_t)r * 128 + d0) = o;
}

// ---------------------------------------------------------------- final head
__global__ __launch_bounds__(256) void k_final(const float* __restrict__ xin,
                                               const float* __restrict__ Wc1,
                                               const float* __restrict__ bc1,
                                               const float* __restrict__ Wc2,
                                               const float* __restrict__ bc2,
                                               float* __restrict__ out, int nRows) {
    __shared__ float xs[32][132];
    __shared__ float w1s[128][64];
    __shared__ float hs[32][68];
    int row0 = blockIdx.x * 32;
    int tid = threadIdx.x;

    for (int i = tid; i < 2048; i += 256) {
        int kk = i >> 4, c4 = (i & 15) << 2;
        *(float4*)&w1s[kk][c4] = *(const float4*)(Wc1 + kk * 64 + c4);
    }
    for (int i = tid; i < 1024; i += 256) {
        int r = i >> 5, c4 = (i & 31) << 2;
        int row = row0 + r;
        float4 o = make_float4(0.f, 0.f, 0.f, 0.f);
        if (row < nRows) o = *(const float4*)(xin + (size_t)row * 128 + c4);
        *(float4*)&xs[r][c4] = o;
    }
    __syncthreads();

    int cg = tid & 15, rg = tid >> 4;
    int c0 = cg * 4, r0 = rg * 2;
    float acc[2][4];
    float4 bc = *(const float4*)(bc1 + c0);
    acc[0][0] = bc.x; acc[0][1] = bc.y; acc[0][2] = bc.z; acc[0][3] = bc.w;
    acc[1][0] = bc.x; acc[1][1] = bc.y; acc[1][2] = bc.z; acc[1][3] = bc.w;
    for (int k = 0; k < 128; ++k) {
        float4 w4 = *(const float4*)&w1s[k][c0];
        float x0 = xs[r0][k], x1 = xs[r0 + 1][k];
        acc[0][0] = fmaf(x0, w4.x, acc[0][0]);
        acc[0][1] = fmaf(x0, w4.y, acc[0][1]);
        acc[0][2] = fmaf(x0, w4.z, acc[0][2]);
        acc[0][3] = fmaf(x0, w4.w, acc[0][3]);
        acc[1][0] = fmaf(x1, w4.x, acc[1][0]);
        acc[1][1] = fmaf(x1, w4.y, acc[1][1]);
        acc[1][2] = fmaf(x1, w4.z, acc[1][2]);
        acc[1][3] = fmaf(x1, w4.w, acc[1][3]);
    }
    *(float4*)&hs[r0][c0] = make_float4(fmaxf(acc[0][0], 0.f), fmaxf(acc[0][1], 0.f),
                                        fmaxf(acc[0][2], 0.f), fmaxf(acc[0][3], 0.f));
    *(float4*)&hs[r0 + 1][c0] = make_float4(fmaxf(acc[1][0], 0.f), fmaxf(acc[1][1], 0.f),
                                            fmaxf(acc[1][2], 0.f), fmaxf(acc[1][3], 0.f));
    __syncthreads();

    if (tid < 64) {
        int r = tid >> 1, oc = tid & 1;
        float s = bc2[oc];
        for (int c = 0; c < 64; ++c) s = fmaf(hs[r][c], Wc2[c * 2 + oc], s);
        int row = row0 + r;
        if (row < nRows) out[(size_t)row * 2 + oc] = s;
    }
}

// ---------------------------------------------------------------- launch
extern "C" void kernel_launch(void* const* d_in, const int* in_sizes, int n_in,
                              void* d_out, int out_size, void* d_ws, size_t ws_size,
                              hipStream_t stream) {
    const float* x   = (const float*)d_in[0];
    const int*   ei  = (const int*)d_in[1];
    const float* W1  = (const float*)d_in[2];
    const float* b1  = (const float*)d_in[3];
    const float* g1  = (const float*)d_in[4];
    const float* be1 = (const float*)d_in[5];
    const float* m1  = (const float*)d_in[6];
    const float* v1  = (const float*)d_in[7];
    const float* W2  = (const float*)d_in[8];
    const float* b2  = (const float*)d_in[9];
    const float* g2  = (const float*)d_in[10];
    const float* be2 = (const float*)d_in[11];
    const float* m2  = (const float*)d_in[12];
    const float* v2  = (const float*)d_in[13];
    const float* Wc1 = (const float*)d_in[14];
    const float* bc1 = (const float*)d_in[15];
    const float* Wc2 = (const float*)d_in[16];
    const float* bc2 = (const float*)d_in[17];

    const int N_ = in_sizes[0] / 128;
    const int E_ = in_sizes[1] / 2;
    const int* srci = ei;
    const int* dsti = ei + E_;

    float* A = (float*)d_ws;                       // [N,128]
    float* B = A + (size_t)N_ * 128;               // [N,128]; rank aliases B
    int* rank = (int*)B;                           // [E] int, dead before gather-1
    int* counts   = (int*)(B + (size_t)N_ * 128);  // N
    int* rowstart = counts + N_;                   // N+1
    int* bsums    = rowstart + N_ + 1;             // 256
    int* col      = bsums + 256;                   // E

    const int nb = (N_ + 2047) / 2048;

    // linear-1 split into two row-halves, co-dispatched with CSR passes
    const int H1  = ((N_ / 2 + 63) / 64) * 64;     // first-half row limit (x64)
    const int LB1 = H1 / 64;
    const int LB2 = (N_ - H1 + 63) / 64;
    const int HB  = (E_ + 255) / 256;              // histrank blocks
    const int FB  = HB;                            // fill blocks

    hipMemsetAsync(counts, 0, (size_t)N_ * sizeof(int), stream);

    // CSR pass 1 (histrank) || linear-1 rows [0,H1)
    k_hist_lin<<<HB + LB1, 256, 0, stream>>>(dsti, counts, rank, E_, HB,
                                             x, W1, b1, A, H1 < N_ ? H1 : N_);
    k_scan1<<<nb, 256, 0, stream>>>(counts, bsums, N_);
    k_scan2<<<1, 64, 0, stream>>>(bsums, nb);
    k_scan3<<<nb, 256, 0, stream>>>(counts, bsums, rowstart, N_, E_);

    // CSR pass 2 (fill) || linear-1 rows [H1,N)
    k_fill_lin<<<FB + LB2, 256, 0, stream>>>(srci, dsti, rank, rowstart, col, E_, FB,
                                             x, W1, b1, A, H1, N_);

    // layer 1 aggregate + bn1 + relu
    k_gather<true><<<(N_ + 3) / 4, 256, 0, stream>>>(A, rowstart, col,
                                                     g1, be1, m1, v1, B, N_);

    // layer 2 linear
    k_linear<<<(N_ + 63) / 64, 256, 0, stream>>>(B, W2, b2, A, N_);

    // layer 2 aggregate + bn2 + relu
    k_gather<true><<<(N_ + 3) / 4, 256, 0, stream>>>(A, rowstart, col,
                                                     g2, be2, m2, v2, B, N_);

    // MLP head
    k_final<<<(N_ + 31) / 32, 256, 0, stream>>>(B, Wc1, bc1, Wc2, bc2,
                                                (float*)d_out, N_);
}

// Round 7
// 644.620 us; speedup vs baseline: 1.2663x; 1.0171x over previous
//
#include <hip/hip_runtime.h>
#include <hip/hip_bf16.h>

#define EPS 1e-5f

// ---------------------------------------------------------------- histogram + rank
// rank[e] = arrival order of edge e within its dst. One atomic pass; rank is
// written LINEARLY (streaming, non-temporal: keep L2 for the counts RMWs).
__global__ __launch_bounds__(256) void k_histrank(const int* __restrict__ dst,
                                                  int* __restrict__ counts,
                                                  int* __restrict__ rank, int nE) {
    int i = blockIdx.x * 256 + threadIdx.x;
    if (i < nE) {
        int p = atomicAdd(&counts[dst[i]], 1);
        __builtin_nontemporal_store(p, &rank[i]);
    }
}

// ---------------------------------------------------------------- scan (3 phases)
__global__ __launch_bounds__(256) void k_scan1(const int* __restrict__ counts,
                                               int* __restrict__ bsums, int n) {
    __shared__ int sdata[256];
    int base = blockIdx.x * 2048;
    int t = threadIdx.x;
    int s = 0;
#pragma unroll
    for (int i = 0; i < 8; ++i) {
        int idx = base + t * 8 + i;
        if (idx < n) s += counts[idx];
    }
    sdata[t] = s;
    __syncthreads();
    for (int off = 128; off > 0; off >>= 1) {
        if (t < off) sdata[t] += sdata[t + off];
        __syncthreads();
    }
    if (t == 0) bsums[blockIdx.x] = sdata[0];
}

__global__ __launch_bounds__(64) void k_scan2(int* __restrict__ bsums, int nb) {
    if (threadIdx.x == 0 && blockIdx.x == 0) {
        int acc = 0;
        for (int i = 0; i < nb; ++i) { int v = bsums[i]; bsums[i] = acc; acc += v; }
    }
}

__global__ __launch_bounds__(256) void k_scan3(const int* __restrict__ counts,
                                               const int* __restrict__ bsums,
                                               int* __restrict__ rowstart,
                                               int n, int nE) {
    __shared__ int sth[256];
    int base = blockIdx.x * 2048;
    int t = threadIdx.x;
    int loc[8];
    int s = 0;
#pragma unroll
    for (int i = 0; i < 8; ++i) {
        int idx = base + t * 8 + i;
        loc[i] = s;
        s += (idx < n) ? counts[idx] : 0;
    }
    sth[t] = s;
    __syncthreads();
    for (int off = 1; off < 256; off <<= 1) {
        int tmp = (t >= off) ? sth[t - off] : 0;
        __syncthreads();
        sth[t] += tmp;
        __syncthreads();
    }
    int excl = sth[t] - s + bsums[blockIdx.x];
#pragma unroll
    for (int i = 0; i < 8; ++i) {
        int idx = base + t * 8 + i;
        if (idx < n) rowstart[idx] = excl + loc[i];
    }
    if (blockIdx.x == 0 && t == 0) rowstart[n] = nE;
}

// ---------------------------------------------------------------- CSR fill (no atomics)
__global__ __launch_bounds__(256) void k_fill3(const int* __restrict__ srci,
                                               const int* __restrict__ dsti,
                                               const int* __restrict__ rank,
                                               const int* __restrict__ rowstart,
                                               int* __restrict__ col, int nE) {
    int e = blockIdx.x * 256 + threadIdx.x;
    if (e < nE) {
        col[rowstart[dsti[e]] + rank[e]] = srci[e];
    }
}

// ---------------------------------------------------------------- linear
__global__ __launch_bounds__(256) void k_linear(const float* __restrict__ X,
                                                const float* __restrict__ W,
                                                const float* __restrict__ bias,
                                                float* __restrict__ out,
                                                int nRows) {
    __shared__ float xs[64][132];
    int row0 = blockIdx.x * 64;
    int tid = threadIdx.x;
    for (int i = tid; i < 64 * 32; i += 256) {
        int r = i >> 5, c4 = (i & 31) << 2;
        float4 v = make_float4(0.f, 0.f, 0.f, 0.f);
        int row = row0 + r;
        if (row < nRows) v = *(const float4*)(X + (size_t)row * 128 + c4);
        *(float4*)&xs[r][c4] = v;
    }
    __syncthreads();

    int cg = tid & 15, rg = tid >> 4;
    int c0 = cg * 8, r0 = rg * 4;
    float acc[4][8];
    float4 b0 = *(const float4*)(bias + c0);
    float4 b1 = *(const float4*)(bias + c0 + 4);
#pragma unroll
    for (int r = 0; r < 4; ++r) {
        acc[r][0] = b0.x; acc[r][1] = b0.y; acc[r][2] = b0.z; acc[r][3] = b0.w;
        acc[r][4] = b1.x; acc[r][5] = b1.y; acc[r][6] = b1.z; acc[r][7] = b1.w;
    }

    for (int k0 = 0; k0 < 128; k0 += 4) {
        float4 xv[4];
#pragma unroll
        for (int r = 0; r < 4; ++r) xv[r] = *(const float4*)&xs[r0 + r][k0];
#pragma unroll
        for (int kk = 0; kk < 4; ++kk) {
            int k = k0 + kk;
            float4 w0 = *(const float4*)(W + k * 128 + c0);
            float4 w1 = *(const float4*)(W + k * 128 + c0 + 4);
            float wv[8] = {w0.x, w0.y, w0.z, w0.w, w1.x, w1.y, w1.z, w1.w};
#pragma unroll
            for (int r = 0; r < 4; ++r) {
                float xk = (&xv[r].x)[kk];
#pragma unroll
                for (int j = 0; j < 8; ++j) acc[r][j] = fmaf(xk, wv[j], acc[r][j]);
            }
        }
    }

#pragma unroll
    for (int r = 0; r < 4; ++r) {
        int row = row0 + r0 + r;
        if (row >= nRows) continue;
        *(float4*)(out + (size_t)row * 128 + c0) =
            make_float4(acc[r][0], acc[r][1], acc[r][2], acc[r][3]);
        *(float4*)(out + (size_t)row * 128 + c0 + 4) =
            make_float4(acc[r][4], acc[r][5], acc[r][6], acc[r][7]);
    }
}

// ---------------------------------------------------------------- gather (float4 half-split)
// one wave per dst row. lane covers dims [4*(lane&31), +4); the two 32-lane
// halves process interleaved cols (even/odd within the row's col range).
// Halves combined via shfl_xor(32); half 0 applies BN and writes the row.
template <bool FUSE_BN>
__global__ __launch_bounds__(256) void k_gather(const float* __restrict__ src,
                                                const int* __restrict__ rowstart,
                                                const int* __restrict__ col,
                                                const float* __restrict__ g,
                                                const float* __restrict__ be,
                                                const float* __restrict__ m,
                                                const float* __restrict__ v,
                                                float* __restrict__ out, int nRows) {
    int r = blockIdx.x * 4 + (threadIdx.x >> 6);
    if (r >= nRows) return;
    int lane = threadIdx.x & 63;
    int half = lane >> 5;
    int li = lane & 31;
    int d0 = li * 4;
    int s = rowstart[r], e = rowstart[r + 1];
    int deg = e - s;

    float4 acc = make_float4(0.f, 0.f, 0.f, 0.f);
    if (half == 0) acc = *(const float4*)(src + (size_t)r * 128 + d0);   // self loop

    int nP = deg >> 1;          // col pairs (one col per half per pair)
    int p = 0;
    for (; p + 4 <= nP; p += 4) {                 // 8 cols/iter (4 per half)
        int jb = s + 2 * p + half;
        int c0i = col[jb], c1i = col[jb + 2], c2i = col[jb + 4], c3i = col[jb + 6];
        float4 t0 = *(const float4*)(src + (size_t)c0i * 128 + d0);
        float4 t1 = *(const float4*)(src + (size_t)c1i * 128 + d0);
        float4 t2 = *(const float4*)(src + (size_t)c2i * 128 + d0);
        float4 t3 = *(const float4*)(src + (size_t)c3i * 128 + d0);
        acc.x += (t0.x + t1.x) + (t2.x + t3.x);
        acc.y += (t0.y + t1.y) + (t2.y + t3.y);
        acc.z += (t0.z + t1.z) + (t2.z + t3.z);
        acc.w += (t0.w + t1.w) + (t2.w + t3.w);
    }
    for (; p < nP; ++p) {                         // 2 cols/iter
        int ci = col[s + 2 * p + half];
        float4 t = *(const float4*)(src + (size_t)ci * 128 + d0);
        acc.x += t.x; acc.y += t.y; acc.z += t.z; acc.w += t.w;
    }
    if ((deg & 1) && half == 0) {                 // odd leftover col
        int ci = col[e - 1];
        float4 t = *(const float4*)(src + (size_t)ci * 128 + d0);
        acc.x += t.x; acc.y += t.y; acc.z += t.z; acc.w += t.w;
    }

    // combine halves (lane ^ 32)
    acc.x += __shfl_xor(acc.x, 32, 64);
    acc.y += __shfl_xor(acc.y, 32, 64);
    acc.z += __shfl_xor(acc.z, 32, 64);
    acc.w += __shfl_xor(acc.w, 32, 64);

    if (half == 0) {
        float rc = 1.0f / (float)(deg + 1);
        float4 o;
        if (FUSE_BN) {
            float4 gv  = *(const float4*)(g + d0);
            float4 bev = *(const float4*)(be + d0);
            float4 mv  = *(const float4*)(m + d0);
            float4 vv  = *(const float4*)(v + d0);
            o.x = fmaxf((acc.x * rc - mv.x) * rsqrtf(vv.x + EPS) * gv.x + bev.x, 0.f);
            o.y = fmaxf((acc.y * rc - mv.y) * rsqrtf(vv.y + EPS) * gv.y + bev.y, 0.f);
            o.z = fmaxf((acc.z * rc - mv.z) * rsqrtf(vv.z + EPS) * gv.z + bev.z, 0.f);
            o.w = fmaxf((acc.w * rc - mv.w) * rsqrtf(vv.w + EPS) * gv.w + bev.w, 0.f);
        } else {
            o.x = acc.x * rc; o.y = acc.y * rc; o.z = acc.z * rc; o.w = acc.w * rc;
        }
        *(float4*)(out + (size_t)r * 128 + d0) = o;
    }
}

// ---------------------------------------------------------------- final head
__global__ __launch_bounds__(256) void k_final(const float* __restrict__ xin,
                                               const float* __restrict__ Wc1,
                                               const float* __restrict__ bc1,
                                               const float* __restrict__ Wc2,
                                               const float* __restrict__ bc2,
                                               float* __restrict__ out, int nRows) {
    __shared__ float xs[32][132];
    __shared__ float w1s[128][64];
    __shared__ float hs[32][68];
    int row0 = blockIdx.x * 32;
    int tid = threadIdx.x;

    for (int i = tid; i < 2048; i += 256) {
        int kk = i >> 4, c4 = (i & 15) << 2;
        *(float4*)&w1s[kk][c4] = *(const float4*)(Wc1 + kk * 64 + c4);
    }
    for (int i = tid; i < 1024; i += 256) {
        int r = i >> 5, c4 = (i & 31) << 2;
        int row = row0 + r;
        float4 o = make_float4(0.f, 0.f, 0.f, 0.f);
        if (row < nRows) o = *(const float4*)(xin + (size_t)row * 128 + c4);
        *(float4*)&xs[r][c4] = o;
    }
    __syncthreads();

    int cg = tid & 15, rg = tid >> 4;
    int c0 = cg * 4, r0 = rg * 2;
    float acc[2][4];
    float4 bc = *(const float4*)(bc1 + c0);
    acc[0][0] = bc.x; acc[0][1] = bc.y; acc[0][2] = bc.z; acc[0][3] = bc.w;
    acc[1][0] = bc.x; acc[1][1] = bc.y; acc[1][2] = bc.z; acc[1][3] = bc.w;
    for (int k = 0; k < 128; ++k) {
        float4 w4 = *(const float4*)&w1s[k][c0];
        float x0 = xs[r0][k], x1 = xs[r0 + 1][k];
        acc[0][0] = fmaf(x0, w4.x, acc[0][0]);
        acc[0][1] = fmaf(x0, w4.y, acc[0][1]);
        acc[0][2] = fmaf(x0, w4.z, acc[0][2]);
        acc[0][3] = fmaf(x0, w4.w, acc[0][3]);
        acc[1][0] = fmaf(x1, w4.x, acc[1][0]);
        acc[1][1] = fmaf(x1, w4.y, acc[1][1]);
        acc[1][2] = fmaf(x1, w4.z, acc[1][2]);
        acc[1][3] = fmaf(x1, w4.w, acc[1][3]);
    }
    *(float4*)&hs[r0][c0] = make_float4(fmaxf(acc[0][0], 0.f), fmaxf(acc[0][1], 0.f),
                                        fmaxf(acc[0][2], 0.f), fmaxf(acc[0][3], 0.f));
    *(float4*)&hs[r0 + 1][c0] = make_float4(fmaxf(acc[1][0], 0.f), fmaxf(acc[1][1], 0.f),
                                            fmaxf(acc[1][2], 0.f), fmaxf(acc[1][3], 0.f));
    __syncthreads();

    if (tid < 64) {
        int r = tid >> 1, oc = tid & 1;
        float s = bc2[oc];
        for (int c = 0; c < 64; ++c) s = fmaf(hs[r][c], Wc2[c * 2 + oc], s);
        int row = row0 + r;
        if (row < nRows) out[(size_t)row * 2 + oc] = s;
    }
}

// ---------------------------------------------------------------- launch
extern "C" void kernel_launch(void* const* d_in, const int* in_sizes, int n_in,
                              void* d_out, int out_size, void* d_ws, size_t ws_size,
                              hipStream_t stream) {
    const float* x   = (const float*)d_in[0];
    const int*   ei  = (const int*)d_in[1];
    const float* W1  = (const float*)d_in[2];
    const float* b1  = (const float*)d_in[3];
    const float* g1  = (const float*)d_in[4];
    const float* be1 = (const float*)d_in[5];
    const float* m1  = (const float*)d_in[6];
    const float* v1  = (const float*)d_in[7];
    const float* W2  = (const float*)d_in[8];
    const float* b2  = (const float*)d_in[9];
    const float* g2  = (const float*)d_in[10];
    const float* be2 = (const float*)d_in[11];
    const float* m2  = (const float*)d_in[12];
    const float* v2  = (const float*)d_in[13];
    const float* Wc1 = (const float*)d_in[14];
    const float* bc1 = (const float*)d_in[15];
    const float* Wc2 = (const float*)d_in[16];
    const float* bc2 = (const float*)d_in[17];

    const int N_ = in_sizes[0] / 128;
    const int E_ = in_sizes[1] / 2;
    const int* srci = ei;
    const int* dsti = ei + E_;

    float* A = (float*)d_ws;                       // [N,128]
    float* B = A + (size_t)N_ * 128;               // [N,128]; rank aliases B
    int* rank = (int*)B;                           // [E] int, dead before gather-1
    int* counts   = (int*)(B + (size_t)N_ * 128);  // N
    int* rowstart = counts + N_;                   // N+1
    int* bsums    = rowstart + N_ + 1;             // 256
    int* col      = bsums + 256;                   // E

    const int nb = (N_ + 2047) / 2048;

    // ---- CSR build (rank trick: single atomic pass, atomic-free fill)
    hipMemsetAsync(counts, 0, (size_t)N_ * sizeof(int), stream);
    k_histrank<<<(E_ + 255) / 256, 256, 0, stream>>>(dsti, counts, rank, E_);
    k_scan1   <<<nb, 256, 0, stream>>>(counts, bsums, N_);
    k_scan2   <<<1, 64, 0, stream>>>(bsums, nb);
    k_scan3   <<<nb, 256, 0, stream>>>(counts, bsums, rowstart, N_, E_);
    k_fill3   <<<(E_ + 255) / 256, 256, 0, stream>>>(srci, dsti, rank, rowstart,
                                                     col, E_);

    // ---- layer 1
    k_linear<<<(N_ + 63) / 64, 256, 0, stream>>>(x, W1, b1, A, N_);
    k_gather<true><<<(N_ + 3) / 4, 256, 0, stream>>>(A, rowstart, col,
                                                     g1, be1, m1, v1, B, N_);

    // ---- layer 2
    k_linear<<<(N_ + 63) / 64, 256, 0, stream>>>(B, W2, b2, A, N_);
    k_gather<true><<<(N_ + 3) / 4, 256, 0, stream>>>(A, rowstart, col,
                                                     g2, be2, m2, v2, B, N_);

    // ---- MLP head
    k_final<<<(N_ + 31) / 32, 256, 0, stream>>>(B, Wc1, bc1, Wc2, bc2,
                                                (float*)d_out, N_);
}